// Round 13
// baseline (132.773 us; speedup 1.0000x reference)
//
#include <hip/hip_runtime.h>
#include <math.h>

// Problem constants (from reference)
constexpr int B_  = 16;
constexpr int LQ_ = 1024;
constexpr int LK_ = 4096;
constexpr int D_  = 256;
constexpr float HALF_BW_F = 64.0f;         // 128 // 2
constexpr float SCALE = 0.0625f;           // (D^-0.25)^2 = 1/sqrt(256)

// native clang vector for nontemporal builtins (HIP_vector_type is rejected)
typedef float fx4 __attribute__((ext_vector_type(4)));

// softmax covers 9*16 = 144 slots; pad to 168 (168 % 32 == 8 -> the 4
// per-row arrays start on different banks)
constexpr int NB_PAD = 168;
constexpr int ROWS_PER_BLK = 16;                 // 4 waves x 4 rows
constexpr int NUNIT = (B_ * LQ_) / ROWS_PER_BLK; // 1024 row-units
constexpr int NXCD = 8;
constexpr int UNIT_PER_XCD = NUNIT / NXCD;       // 128

// DPP row_shr:N — lane i receives from lane i-N (toward higher lanes) within
// the 16-lane DPP row; out-of-range sources read 0 (bound_ctrl=1). After
// shr8,shr4,shr2,shr1 the complete 16-lane sum is in the row's last lane
// (l==15).
template <int CTRL>
__device__ __forceinline__ float dpp_add(float v) {
    int x = __builtin_amdgcn_update_dpp(0, __float_as_int(v), CTRL, 0xF, 0xF, true);
    return v + __int_as_float(x);
}

// reductions within a 16-lane group (xor offsets stay inside the group)
__device__ __forceinline__ float grp16_max(float v) {
    #pragma unroll
    for (int off = 8; off > 0; off >>= 1)
        v = fmaxf(v, __shfl_xor(v, off, 64));
    return v;
}
__device__ __forceinline__ float grp16_sum(float v) {
    #pragma unroll
    for (int off = 8; off > 0; off >>= 1)
        v += __shfl_xor(v, off, 64);
    return v;
}

// Two sequential kernels (temporal decoupling): within one wave — and even
// across co-resident waves on one CU — store drain and load latency ADD
// (vmcnt retires in issue order; store backpressure stalls the CU VMEM
// port). Rounds 9-12: after/before/paced/specialized = 120.7/114.7/118.3/
// 100.4 us. So run the store pump and the compute phase as separate
// dispatches, each at its own ceiling. Address partition is exact: kernel A
// writes band stripes (+V), kernel B writes all non-band stripes.

// ================= KERNEL A: compute =================
__global__ __launch_bounds__(256, 4) void compute_kernel(
    const float* __restrict__ Q, const float* __restrict__ K,
    const float* __restrict__ V,
    const int* __restrict__ qlen, const int* __restrict__ klen,
    float* __restrict__ Wout, float* __restrict__ Vout)
{
    const int Bid  = blockIdx.x;
    // XCD-aware swizzle: each XCD owns 128 consecutive units (2048 rows =
    // 2 batches) -> sliding K-band stays in its private 4 MB L2.
    const int rb   = (Bid & (NXCD - 1)) * UNIT_PER_XCD + (Bid >> 3);
    const int tid  = threadIdx.x;
    const int lane = tid & 63;
    const int wave = tid >> 6;
    const int row0 = rb * ROWS_PER_BLK + wave * 4;   // first of this wave's 4 rows
    const int b    = row0 >> 10;
    const int qi0  = row0 & (LQ_ - 1);
    const int g    = lane >> 4;            // key slot 0..3 within wave
    const int l    = lane & 15;            // D-chunk 0..15 (16 floats each)

    __shared__ float s_sc[4][4 * NB_PAD];  // [wave][row*NB_PAD + slot]

    const int   key_len = klen[b];
    const float slope   = (float)key_len / (float)qlen[b];   // fp32 div (ref)

    // per-row integer band (exact fp32 arithmetic as reference)
    int k_lo[4], k_hi[4];                  // only static-indexed below
    #pragma unroll
    for (int r = 0; r < 4; ++r) {
        const float center = (float)(qi0 + r) * slope;
        int lo = (int)ceilf(center - HALF_BW_F); if (lo < 0) lo = 0;
        int hi = (int)floorf(center + HALF_BW_F); if (hi > key_len - 1) hi = key_len - 1;
        k_lo[r] = lo; k_hi[r] = hi;
    }
    const int lo0 = k_lo[0], hi3 = k_hi[3];    // union band (nondecreasing)

    // ---- Q staging: 4 rows x 4 float4 (lane l covers floats l*16..l*16+15)
    const float* qbase = Q + ((size_t)b * LQ_ + qi0) * D_;
    float4 q0[4], q1[4], q2[4], q3[4];
    #pragma unroll
    for (int m = 0; m < 4; ++m) {
        q0[m] = *(const float4*)(qbase + 0 * D_ + l * 16 + m * 4);
        q1[m] = *(const float4*)(qbase + 1 * D_ + l * 16 + m * 4);
        q2[m] = *(const float4*)(qbase + 2 * D_ + l * 16 + m * 4);
        q3[m] = *(const float4*)(qbase + 3 * D_ + l * 16 + m * 4);
    }

    // ---- scores: 4 keys/iter (one per 16-lane group), each serves 4 rows --
    const float* kbase = K + (size_t)b * LK_ * D_;
    float* sw = s_sc[wave];
    for (int kk0 = lo0; kk0 <= hi3; kk0 += 4) {
        const int key  = kk0 + g;
        const int keyc = (key <= hi3) ? key : hi3;   // clamp: safe, in-batch
        const float* kp = kbase + (size_t)keyc * D_ + l * 16;
        float4 kf[4];
        #pragma unroll
        for (int m = 0; m < 4; ++m)
            kf[m] = *(const float4*)(kp + m * 4);    // 4 loads in flight
        float a0 = 0.f, a1 = 0.f, a2 = 0.f, a3 = 0.f;
        #pragma unroll
        for (int m = 0; m < 4; ++m) {
            a0 += q0[m].x*kf[m].x + q0[m].y*kf[m].y + q0[m].z*kf[m].z + q0[m].w*kf[m].w;
            a1 += q1[m].x*kf[m].x + q1[m].y*kf[m].y + q1[m].z*kf[m].z + q1[m].w*kf[m].w;
            a2 += q2[m].x*kf[m].x + q2[m].y*kf[m].y + q2[m].z*kf[m].z + q2[m].w*kf[m].w;
            a3 += q3[m].x*kf[m].x + q3[m].y*kf[m].y + q3[m].z*kf[m].z + q3[m].w*kf[m].w;
        }
        // 16-lane reduce per row-acc; complete sums land in l==15
        a0 = dpp_add<0x118>(a0); a0 = dpp_add<0x114>(a0);
        a0 = dpp_add<0x112>(a0); a0 = dpp_add<0x111>(a0);
        a1 = dpp_add<0x118>(a1); a1 = dpp_add<0x114>(a1);
        a1 = dpp_add<0x112>(a1); a1 = dpp_add<0x111>(a1);
        a2 = dpp_add<0x118>(a2); a2 = dpp_add<0x114>(a2);
        a2 = dpp_add<0x112>(a2); a2 = dpp_add<0x111>(a2);
        a3 = dpp_add<0x118>(a3); a3 = dpp_add<0x114>(a3);
        a3 = dpp_add<0x112>(a3); a3 = dpp_add<0x111>(a3);
        if (l == 15) {   // key unclamped in conditions -> clamped dup never stores
            if (key >= k_lo[0] && key <= k_hi[0]) sw[0*NB_PAD + key - k_lo[0]] = a0 * SCALE;
            if (key >= k_lo[1] && key <= k_hi[1]) sw[1*NB_PAD + key - k_lo[1]] = a1 * SCALE;
            if (key >= k_lo[2] && key <= k_hi[2]) sw[2*NB_PAD + key - k_lo[2]] = a2 * SCALE;
            if (key >= k_lo[3] && key <= k_hi[3]) sw[3*NB_PAD + key - k_lo[3]] = a3 * SCALE;
        }
    }

    // ---- softmax: 16-lane group g owns row g (9 values per lane) ----
    // recompute band from scalars (k_lo[g] with runtime g would spill, rule #20)
    const float center_g = (float)(qi0 + g) * slope;
    int klo_g = (int)ceilf(center_g - HALF_BW_F); if (klo_g < 0) klo_g = 0;
    int khi_g = (int)floorf(center_g + HALF_BW_F); if (khi_g > key_len - 1) khi_g = key_len - 1;
    const int nb_g = khi_g - klo_g + 1;    // 65..129
    float* sg = sw + g * NB_PAD;

    float vj[9];
    #pragma unroll
    for (int j = 0; j < 9; ++j) {
        const int idx = l + j * 16;
        vj[j] = (idx < nb_g) ? sg[idx] : -INFINITY;
    }
    float mx = vj[0];
    #pragma unroll
    for (int j = 1; j < 9; ++j) mx = fmaxf(mx, vj[j]);
    mx = grp16_max(mx);

    float ej[9], ssum = 0.f;
    #pragma unroll
    for (int j = 0; j < 9; ++j) { ej[j] = __expf(vj[j] - mx); ssum += ej[j]; }
    ssum = grp16_sum(ssum);
    const float inv = 1.0f / ssum;
    #pragma unroll
    for (int j = 0; j < 9; ++j)
        sg[l + j * 16] = ej[j] * inv;      // padding slots get 0, never read

    // ---- band stripes only (<=2 per row; fill kernel writes the rest) ----
    #pragma unroll
    for (int r = 0; r < 4; ++r) {
        const int klo = k_lo[r], khi = k_hi[r];
        const int s_lo = klo >> 8, s_hi = khi >> 8;
        float* base = Wout + (size_t)(row0 + r) * LK_;
        const float* sr = sw + r * NB_PAD;
        for (int j = s_lo; j <= s_hi; ++j) {           // <=2 iterations
            const int c0 = (j * 64 + lane) * 4;        // column of this float4
            float w[4] = {0.f, 0.f, 0.f, 0.f};
            if (c0 + 3 >= klo && c0 <= khi) {
                #pragma unroll
                for (int i = 0; i < 4; ++i) {
                    const int c = c0 + i;
                    if (c >= klo && c <= khi) w[i] = sr[c - klo];
                }
            }
            fx4 w4; w4.x = w[0]; w4.y = w[1]; w4.z = w[2]; w4.w = w[3];
            __builtin_nontemporal_store(w4, (fx4*)(base + c0));
        }
    }

    // ---- V copy at wave tail: 4 rows (drain overlaps other waves) ----
    {
        const float* vs = V    + (size_t)row0 * 1024;
        float*       vd = Vout + (size_t)row0 * 1024;
        #pragma unroll
        for (int it = 0; it < 16; ++it) {
            const int o = (it * 64 + lane) * 4;
            fx4 t = __builtin_nontemporal_load((const fx4*)(vs + o));
            __builtin_nontemporal_store(t, (fx4*)(vd + o));
        }
    }
}

// ================= KERNEL B: zero-fill pump =================
// Pure store kernel (the pattern that measures ~7 TB/s). Writes every
// stripe OUTSIDE each row's band-stripe range. Tiny VGPR -> max occupancy.
__global__ void fill_kernel(
    const int* __restrict__ qlen, const int* __restrict__ klen,
    float* __restrict__ Wout)
{
    const int Bid  = blockIdx.x;
    const int rb   = (Bid & (NXCD - 1)) * UNIT_PER_XCD + (Bid >> 3);
    const int tid  = threadIdx.x;
    const int lane = tid & 63;
    const int wave = tid >> 6;
    const int row0 = rb * ROWS_PER_BLK + wave * 4;
    const int b    = row0 >> 10;
    const int qi0  = row0 & (LQ_ - 1);

    const int   key_len = klen[b];
    const float slope   = (float)key_len / (float)qlen[b];

    const fx4 z4 = {0.f, 0.f, 0.f, 0.f};
    #pragma unroll
    for (int r = 0; r < 4; ++r) {
        const float center = (float)(qi0 + r) * slope;
        int lo = (int)ceilf(center - HALF_BW_F); if (lo < 0) lo = 0;
        int hi = (int)floorf(center + HALF_BW_F); if (hi > key_len - 1) hi = key_len - 1;
        const int s_lo = lo >> 8, s_hi = hi >> 8;
        float* base = Wout + (size_t)(row0 + r) * LK_;
        #pragma unroll
        for (int j = 0; j < 16; ++j) {
            if (j < s_lo || j > s_hi)
                __builtin_nontemporal_store(z4, (fx4*)(base + (j * 64 + lane) * 4));
        }
    }
}

extern "C" void kernel_launch(void* const* d_in, const int* in_sizes, int n_in,
                              void* d_out, int out_size, void* d_ws, size_t ws_size,
                              hipStream_t stream) {
    // inputs (setup_inputs order): query, key, value, mask, query_lengths, key_lengths
    const float* Q    = (const float*)d_in[0];
    const float* K    = (const float*)d_in[1];
    const float* V    = (const float*)d_in[2];
    const int*   qlen = (const int*)d_in[4];
    const int*   klen = (const int*)d_in[5];

    float* Wout = (float*)d_out;
    const size_t W_ELEMS = (size_t)B_ * LQ_ * LK_;        // 67,108,864
    float* Vout = Wout + W_ELEMS;

    compute_kernel<<<dim3(NUNIT), dim3(256), 0, stream>>>(
        Q, K, V, qlen, klen, Wout, Vout);
    fill_kernel<<<dim3(NUNIT), dim3(256), 0, stream>>>(qlen, klen, Wout);
}

// Round 14
// 105.042 us; speedup vs baseline: 1.2640x; 1.2640x over previous
//
#include <hip/hip_runtime.h>
#include <math.h>

// Problem constants (from reference)
constexpr int B_  = 16;
constexpr int LQ_ = 1024;
constexpr int LK_ = 4096;
constexpr int D_  = 256;
constexpr float HALF_BW_F = 64.0f;         // 128 // 2
constexpr float SCALE = 0.0625f;           // (D^-0.25)^2 = 1/sqrt(256)

// native clang vector for nontemporal builtins (HIP_vector_type is rejected)
typedef float fx4 __attribute__((ext_vector_type(4)));

// softmax covers 9*16 = 144 slots; pad to 168 (168 % 32 == 8 -> the 4
// per-row arrays start on different banks)
constexpr int NB_PAD = 168;
constexpr int ROWS_PER_BLK = 16;                 // 4 waves x 4 rows
constexpr int NUNIT = (B_ * LQ_) / ROWS_PER_BLK; // 1024 row-units
constexpr int NXCD = 8;
constexpr int UNIT_PER_XCD = NUNIT / NXCD;       // 128

// DPP row_shr:N — lane i receives from lane i-N (toward higher lanes) within
// the 16-lane DPP row; out-of-range sources read 0 (bound_ctrl=1). After
// shr8,shr4,shr2,shr1 the complete 16-lane sum is in the row's last lane
// (l==15).
template <int CTRL>
__device__ __forceinline__ float dpp_add(float v) {
    int x = __builtin_amdgcn_update_dpp(0, __float_as_int(v), CTRL, 0xF, 0xF, true);
    return v + __int_as_float(x);
}

// reductions within a 16-lane group (xor offsets stay inside the group)
__device__ __forceinline__ float grp16_max(float v) {
    #pragma unroll
    for (int off = 8; off > 0; off >>= 1)
        v = fmaxf(v, __shfl_xor(v, off, 64));
    return v;
}
__device__ __forceinline__ float grp16_sum(float v) {
    #pragma unroll
    for (int off = 8; off > 0; off >>= 1)
        v += __shfl_xor(v, off, 64);
    return v;
}

// Round-12 structure (best: 100.4 us) + K/Q LAYOUT FIX.
// The old chunk assignment gave lane (g,l) dims [l*16 + m*4): per-instruction
// lane stride 64B -> 64 distinct 64B lines touched, 16B consumed each =
// 4x L1 transaction amplification (256 txns per 4KB iteration). New
// assignment: lane (g,l) owns dims [m*64 + l*4): per instruction each
// 16-lane group reads a CONTIGUOUS 256B -> 64 txns/iter (ideal). Dot
// products are dim-order-agnostic; the DPP 16-lane reduce is unchanged.
__global__ __launch_bounds__(256, 4) void stripe_attn_kernel(
    const float* __restrict__ Q, const float* __restrict__ K,
    const float* __restrict__ V,
    const int* __restrict__ qlen, const int* __restrict__ klen,
    float* __restrict__ Wout, float* __restrict__ Vout)
{
    const int Bid  = blockIdx.x;
    const int xcd  = Bid & 7;
    const int type = (Bid >> 3) & 1;
    // unit u in [0,1024): XCD-contiguous row mapping (each XCD owns 2048
    // consecutive rows = 2 batches -> sliding K-band stays in its 4MB L2)
    const int rb   = xcd * UNIT_PER_XCD + (Bid >> 4);
    const int tid  = threadIdx.x;
    const int lane = tid & 63;
    const int wave = tid >> 6;
    const int row0 = rb * ROWS_PER_BLK + wave * 4;   // first of this wave's 4 rows
    const int b    = row0 >> 10;           // same batch for all 16 unit rows
    const int qi0  = row0 & (LQ_ - 1);

    __shared__ float s_sc[4][4 * NB_PAD];  // [wave][row*NB_PAD + slot]

    const int   key_len = klen[b];
    const float slope   = (float)key_len / (float)qlen[b];   // fp32 div (ref)

    // per-row integer band (exact fp32 arithmetic as reference)
    int k_lo[4], k_hi[4];                  // only static-indexed below
    #pragma unroll
    for (int r = 0; r < 4; ++r) {
        const float center = (float)(qi0 + r) * slope;
        int lo = (int)ceilf(center - HALF_BW_F); if (lo < 0) lo = 0;
        int hi = (int)floorf(center + HALF_BW_F); if (hi > key_len - 1) hi = key_len - 1;
        k_lo[r] = lo; k_hi[r] = hi;
    }

    if (type == 1) {
        // ================= FILL BLOCK: pure store pump =================
        const float* vs = V    + (size_t)row0 * 1024;
        float*       vd = Vout + (size_t)row0 * 1024;
        #pragma unroll
        for (int it = 0; it < 16; ++it) {
            const int o = (it * 64 + lane) * 4;
            fx4 t = __builtin_nontemporal_load((const fx4*)(vs + o));
            __builtin_nontemporal_store(t, (fx4*)(vd + o));
        }
        const fx4 z4 = {0.f, 0.f, 0.f, 0.f};
        #pragma unroll
        for (int r = 0; r < 4; ++r) {
            const int s_lo = k_lo[r] >> 8, s_hi = k_hi[r] >> 8;
            float* base = Wout + (size_t)(row0 + r) * LK_;
            #pragma unroll
            for (int j = 0; j < 16; ++j) {
                if (j < s_lo || j > s_hi)
                    __builtin_nontemporal_store(z4, (fx4*)(base + (j * 64 + lane) * 4));
            }
        }
        return;
    }

    // ================= COMPUTE BLOCK =================
    const int g   = lane >> 4;             // key slot 0..3 within wave
    const int l   = lane & 15;             // fine chunk 0..15 (4 floats)
    const int lo0 = k_lo[0], hi3 = k_hi[3];    // union band (nondecreasing)

    // ---- Q staging: lane (g,l) holds dims [m*64 + l*4, +4) of each row.
    // Address independent of g -> 4-lane broadcast; per group contiguous.
    const float* qbase = Q + ((size_t)b * LQ_ + qi0) * D_ + l * 4;
    float4 q0[4], q1[4], q2[4], q3[4];
    #pragma unroll
    for (int m = 0; m < 4; ++m) {
        q0[m] = *(const float4*)(qbase + 0 * D_ + m * 64);
        q1[m] = *(const float4*)(qbase + 1 * D_ + m * 64);
        q2[m] = *(const float4*)(qbase + 2 * D_ + m * 64);
        q3[m] = *(const float4*)(qbase + 3 * D_ + m * 64);
    }

    // ---- scores: 4 keys/iter (one per 16-lane group), each serves 4 rows --
    const float* kbase = K + (size_t)b * LK_ * D_ + l * 4;
    float* sw = s_sc[wave];
    for (int kk0 = lo0; kk0 <= hi3; kk0 += 4) {
        const int key  = kk0 + g;
        const int keyc = (key <= hi3) ? key : hi3;   // clamp: safe, in-batch
        const float* kp = kbase + (size_t)keyc * D_;
        float4 kf[4];
        #pragma unroll
        for (int m = 0; m < 4; ++m)
            kf[m] = *(const float4*)(kp + m * 64);   // contiguous 256B/group
        float a0 = 0.f, a1 = 0.f, a2 = 0.f, a3 = 0.f;
        #pragma unroll
        for (int m = 0; m < 4; ++m) {
            a0 += q0[m].x*kf[m].x + q0[m].y*kf[m].y + q0[m].z*kf[m].z + q0[m].w*kf[m].w;
            a1 += q1[m].x*kf[m].x + q1[m].y*kf[m].y + q1[m].z*kf[m].z + q1[m].w*kf[m].w;
            a2 += q2[m].x*kf[m].x + q2[m].y*kf[m].y + q2[m].z*kf[m].z + q2[m].w*kf[m].w;
            a3 += q3[m].x*kf[m].x + q3[m].y*kf[m].y + q3[m].z*kf[m].z + q3[m].w*kf[m].w;
        }
        // 16-lane reduce per row-acc; complete sums land in l==15
        a0 = dpp_add<0x118>(a0); a0 = dpp_add<0x114>(a0);
        a0 = dpp_add<0x112>(a0); a0 = dpp_add<0x111>(a0);
        a1 = dpp_add<0x118>(a1); a1 = dpp_add<0x114>(a1);
        a1 = dpp_add<0x112>(a1); a1 = dpp_add<0x111>(a1);
        a2 = dpp_add<0x118>(a2); a2 = dpp_add<0x114>(a2);
        a2 = dpp_add<0x112>(a2); a2 = dpp_add<0x111>(a2);
        a3 = dpp_add<0x118>(a3); a3 = dpp_add<0x114>(a3);
        a3 = dpp_add<0x112>(a3); a3 = dpp_add<0x111>(a3);
        if (l == 15) {   // key unclamped in conditions -> clamped dup never stores
            if (key >= k_lo[0] && key <= k_hi[0]) sw[0*NB_PAD + key - k_lo[0]] = a0 * SCALE;
            if (key >= k_lo[1] && key <= k_hi[1]) sw[1*NB_PAD + key - k_lo[1]] = a1 * SCALE;
            if (key >= k_lo[2] && key <= k_hi[2]) sw[2*NB_PAD + key - k_lo[2]] = a2 * SCALE;
            if (key >= k_lo[3] && key <= k_hi[3]) sw[3*NB_PAD + key - k_lo[3]] = a3 * SCALE;
        }
    }

    // ---- softmax: 16-lane group g owns row g (9 values per lane) ----
    // recompute band from scalars (k_lo[g] with runtime g would spill, rule #20)
    const float center_g = (float)(qi0 + g) * slope;
    int klo_g = (int)ceilf(center_g - HALF_BW_F); if (klo_g < 0) klo_g = 0;
    int khi_g = (int)floorf(center_g + HALF_BW_F); if (khi_g > key_len - 1) khi_g = key_len - 1;
    const int nb_g = khi_g - klo_g + 1;    // 65..129
    float* sg = sw + g * NB_PAD;

    float vj[9];
    #pragma unroll
    for (int j = 0; j < 9; ++j) {
        const int idx = l + j * 16;
        vj[j] = (idx < nb_g) ? sg[idx] : -INFINITY;
    }
    float mx = vj[0];
    #pragma unroll
    for (int j = 1; j < 9; ++j) mx = fmaxf(mx, vj[j]);
    mx = grp16_max(mx);

    float ej[9], ssum = 0.f;
    #pragma unroll
    for (int j = 0; j < 9; ++j) { ej[j] = __expf(vj[j] - mx); ssum += ej[j]; }
    ssum = grp16_sum(ssum);
    const float inv = 1.0f / ssum;
    #pragma unroll
    for (int j = 0; j < 9; ++j)
        sg[l + j * 16] = ej[j] * inv;      // padding slots get 0, never read

    // ---- band stripes only (<=2 per row; fill partner wrote the rest) ----
    #pragma unroll
    for (int r = 0; r < 4; ++r) {
        const int klo = k_lo[r], khi = k_hi[r];
        const int s_lo = klo >> 8, s_hi = khi >> 8;
        float* base = Wout + (size_t)(row0 + r) * LK_;
        const float* sr = sw + r * NB_PAD;
        for (int j = s_lo; j <= s_hi; ++j) {           // <=2 iterations
            const int c0 = (j * 64 + lane) * 4;        // column of this float4
            float w[4] = {0.f, 0.f, 0.f, 0.f};
            if (c0 + 3 >= klo && c0 <= khi) {
                #pragma unroll
                for (int i = 0; i < 4; ++i) {
                    const int c = c0 + i;
                    if (c >= klo && c <= khi) w[i] = sr[c - klo];
                }
            }
            fx4 w4; w4.x = w[0]; w4.y = w[1]; w4.z = w[2]; w4.w = w[3];
            __builtin_nontemporal_store(w4, (fx4*)(base + c0));
        }
    }
}

extern "C" void kernel_launch(void* const* d_in, const int* in_sizes, int n_in,
                              void* d_out, int out_size, void* d_ws, size_t ws_size,
                              hipStream_t stream) {
    // inputs (setup_inputs order): query, key, value, mask, query_lengths, key_lengths
    const float* Q    = (const float*)d_in[0];
    const float* K    = (const float*)d_in[1];
    const float* V    = (const float*)d_in[2];
    const int*   qlen = (const int*)d_in[4];
    const int*   klen = (const int*)d_in[5];

    float* Wout = (float*)d_out;
    const size_t W_ELEMS = (size_t)B_ * LQ_ * LK_;        // 67,108,864
    float* Vout = Wout + W_ELEMS;

    stripe_attn_kernel<<<dim3(2 * NUNIT), dim3(256), 0, stream>>>(
        Q, K, V, qlen, klen, Wout, Vout);
}

// Round 15
// 99.975 us; speedup vs baseline: 1.3281x; 1.0507x over previous
//
#include <hip/hip_runtime.h>
#include <math.h>

// Problem constants (from reference)
constexpr int B_  = 16;
constexpr int LQ_ = 1024;
constexpr int LK_ = 4096;
constexpr int D_  = 256;
constexpr float HALF_BW_F = 64.0f;         // 128 // 2
constexpr float SCALE = 0.0625f;           // (D^-0.25)^2 = 1/sqrt(256)

// native clang vector for nontemporal builtins (HIP_vector_type is rejected)
typedef float fx4 __attribute__((ext_vector_type(4)));

// softmax covers 9*16 = 144 slots; pad to 168 (168 % 32 == 8 -> the 4
// per-row arrays start on different banks)
constexpr int NB_PAD = 168;
constexpr int ROWS_PER_BLK = 16;                 // 4 waves x 4 rows
constexpr int NUNIT = (B_ * LQ_) / ROWS_PER_BLK; // 1024 row-units
constexpr int NXCD = 8;
constexpr int UNIT_PER_XCD = NUNIT / NXCD;       // 128

// DPP row_shr:N — lane i receives from lane i-N (toward higher lanes) within
// the 16-lane DPP row; out-of-range sources read 0 (bound_ctrl=1). After
// shr8,shr4,shr2,shr1 the complete 16-lane sum is in the row's last lane
// (l==15).
template <int CTRL>
__device__ __forceinline__ float dpp_add(float v) {
    int x = __builtin_amdgcn_update_dpp(0, __float_as_int(v), CTRL, 0xF, 0xF, true);
    return v + __int_as_float(x);
}

// reductions within a 16-lane group (xor offsets stay inside the group)
__device__ __forceinline__ float grp16_max(float v) {
    #pragma unroll
    for (int off = 8; off > 0; off >>= 1)
        v = fmaxf(v, __shfl_xor(v, off, 64));
    return v;
}
__device__ __forceinline__ float grp16_sum(float v) {
    #pragma unroll
    for (int off = 8; off > 0; off >>= 1)
        v += __shfl_xor(v, off, 64);
    return v;
}

// Round-12 structure (best: 100.4 us), ONE lever changed: VGPR budget.
// Register arithmetic: q0-q3 (64) + kf (16) + band arrays (8) + softmax
// temps (18) + addressing (~25-30) = ~130-140 VGPR needed, but
// __launch_bounds__(256,4) capped the allocator at 128 -> inner-loop
// scratch spills (private global-memory traffic every iteration) would
// explain the traffic-/layout-/store-placement-insensitive ~100 us floor
// of rounds 11-14. (256,2) = ~256 VGPR budget, guaranteed spill-free;
// unroll 2 spends the freed regs on cross-iteration load overlap (the
// lever that worked in round 7).
__global__ __launch_bounds__(256, 2) void stripe_attn_kernel(
    const float* __restrict__ Q, const float* __restrict__ K,
    const float* __restrict__ V,
    const int* __restrict__ qlen, const int* __restrict__ klen,
    float* __restrict__ Wout, float* __restrict__ Vout)
{
    const int Bid  = blockIdx.x;
    const int xcd  = Bid & 7;
    const int type = (Bid >> 3) & 1;
    // unit u in [0,1024): XCD-contiguous row mapping (each XCD owns 2048
    // consecutive rows = 2 batches -> sliding K-band stays in its 4MB L2)
    const int rb   = xcd * UNIT_PER_XCD + (Bid >> 4);
    const int tid  = threadIdx.x;
    const int lane = tid & 63;
    const int wave = tid >> 6;
    const int row0 = rb * ROWS_PER_BLK + wave * 4;   // first of this wave's 4 rows
    const int b    = row0 >> 10;           // same batch for all 16 unit rows
    const int qi0  = row0 & (LQ_ - 1);

    __shared__ float s_sc[4][4 * NB_PAD];  // [wave][row*NB_PAD + slot]

    const int   key_len = klen[b];
    const float slope   = (float)key_len / (float)qlen[b];   // fp32 div (ref)

    // per-row integer band (exact fp32 arithmetic as reference)
    int k_lo[4], k_hi[4];                  // only static-indexed below
    #pragma unroll
    for (int r = 0; r < 4; ++r) {
        const float center = (float)(qi0 + r) * slope;
        int lo = (int)ceilf(center - HALF_BW_F); if (lo < 0) lo = 0;
        int hi = (int)floorf(center + HALF_BW_F); if (hi > key_len - 1) hi = key_len - 1;
        k_lo[r] = lo; k_hi[r] = hi;
    }

    if (type == 1) {
        // ================= FILL BLOCK: pure store pump =================
        const float* vs = V    + (size_t)row0 * 1024;
        float*       vd = Vout + (size_t)row0 * 1024;
        #pragma unroll
        for (int it = 0; it < 16; ++it) {
            const int o = (it * 64 + lane) * 4;
            fx4 t = __builtin_nontemporal_load((const fx4*)(vs + o));
            __builtin_nontemporal_store(t, (fx4*)(vd + o));
        }
        const fx4 z4 = {0.f, 0.f, 0.f, 0.f};
        #pragma unroll
        for (int r = 0; r < 4; ++r) {
            const int s_lo = k_lo[r] >> 8, s_hi = k_hi[r] >> 8;
            float* base = Wout + (size_t)(row0 + r) * LK_;
            #pragma unroll
            for (int j = 0; j < 16; ++j) {
                if (j < s_lo || j > s_hi)
                    __builtin_nontemporal_store(z4, (fx4*)(base + (j * 64 + lane) * 4));
            }
        }
        return;
    }

    // ================= COMPUTE BLOCK =================
    const int g   = lane >> 4;             // key slot 0..3 within wave
    const int l   = lane & 15;             // D-chunk 0..15 (16 floats each)
    const int lo0 = k_lo[0], hi3 = k_hi[3];    // union band (nondecreasing)

    // ---- Q staging: 4 rows x 4 float4 (lane l covers floats l*16..l*16+15)
    const float* qbase = Q + ((size_t)b * LQ_ + qi0) * D_;
    float4 q0[4], q1[4], q2[4], q3[4];
    #pragma unroll
    for (int m = 0; m < 4; ++m) {
        q0[m] = *(const float4*)(qbase + 0 * D_ + l * 16 + m * 4);
        q1[m] = *(const float4*)(qbase + 1 * D_ + l * 16 + m * 4);
        q2[m] = *(const float4*)(qbase + 2 * D_ + l * 16 + m * 4);
        q3[m] = *(const float4*)(qbase + 3 * D_ + l * 16 + m * 4);
    }

    // ---- scores: 4 keys/iter (one per 16-lane group), each serves 4 rows --
    const float* kbase = K + (size_t)b * LK_ * D_;
    float* sw = s_sc[wave];
    #pragma unroll 2
    for (int kk0 = lo0; kk0 <= hi3; kk0 += 4) {
        const int key  = kk0 + g;
        const int keyc = (key <= hi3) ? key : hi3;   // clamp: safe, in-batch
        const float* kp = kbase + (size_t)keyc * D_ + l * 16;
        float4 kf[4];
        #pragma unroll
        for (int m = 0; m < 4; ++m)
            kf[m] = *(const float4*)(kp + m * 4);    // 4 loads in flight
        float a0 = 0.f, a1 = 0.f, a2 = 0.f, a3 = 0.f;
        #pragma unroll
        for (int m = 0; m < 4; ++m) {
            a0 += q0[m].x*kf[m].x + q0[m].y*kf[m].y + q0[m].z*kf[m].z + q0[m].w*kf[m].w;
            a1 += q1[m].x*kf[m].x + q1[m].y*kf[m].y + q1[m].z*kf[m].z + q1[m].w*kf[m].w;
            a2 += q2[m].x*kf[m].x + q2[m].y*kf[m].y + q2[m].z*kf[m].z + q2[m].w*kf[m].w;
            a3 += q3[m].x*kf[m].x + q3[m].y*kf[m].y + q3[m].z*kf[m].z + q3[m].w*kf[m].w;
        }
        // 16-lane reduce per row-acc; complete sums land in l==15
        a0 = dpp_add<0x118>(a0); a0 = dpp_add<0x114>(a0);
        a0 = dpp_add<0x112>(a0); a0 = dpp_add<0x111>(a0);
        a1 = dpp_add<0x118>(a1); a1 = dpp_add<0x114>(a1);
        a1 = dpp_add<0x112>(a1); a1 = dpp_add<0x111>(a1);
        a2 = dpp_add<0x118>(a2); a2 = dpp_add<0x114>(a2);
        a2 = dpp_add<0x112>(a2); a2 = dpp_add<0x111>(a2);
        a3 = dpp_add<0x118>(a3); a3 = dpp_add<0x114>(a3);
        a3 = dpp_add<0x112>(a3); a3 = dpp_add<0x111>(a3);
        if (l == 15) {   // key unclamped in conditions -> clamped dup never stores
            if (key >= k_lo[0] && key <= k_hi[0]) sw[0*NB_PAD + key - k_lo[0]] = a0 * SCALE;
            if (key >= k_lo[1] && key <= k_hi[1]) sw[1*NB_PAD + key - k_lo[1]] = a1 * SCALE;
            if (key >= k_lo[2] && key <= k_hi[2]) sw[2*NB_PAD + key - k_lo[2]] = a2 * SCALE;
            if (key >= k_lo[3] && key <= k_hi[3]) sw[3*NB_PAD + key - k_lo[3]] = a3 * SCALE;
        }
    }

    // ---- softmax: 16-lane group g owns row g (9 values per lane) ----
    // recompute band from scalars (k_lo[g] with runtime g would spill, rule #20)
    const float center_g = (float)(qi0 + g) * slope;
    int klo_g = (int)ceilf(center_g - HALF_BW_F); if (klo_g < 0) klo_g = 0;
    int khi_g = (int)floorf(center_g + HALF_BW_F); if (khi_g > key_len - 1) khi_g = key_len - 1;
    const int nb_g = khi_g - klo_g + 1;    // 65..129
    float* sg = sw + g * NB_PAD;

    float vj[9];
    #pragma unroll
    for (int j = 0; j < 9; ++j) {
        const int idx = l + j * 16;
        vj[j] = (idx < nb_g) ? sg[idx] : -INFINITY;
    }
    float mx = vj[0];
    #pragma unroll
    for (int j = 1; j < 9; ++j) mx = fmaxf(mx, vj[j]);
    mx = grp16_max(mx);

    float ej[9], ssum = 0.f;
    #pragma unroll
    for (int j = 0; j < 9; ++j) { ej[j] = __expf(vj[j] - mx); ssum += ej[j]; }
    ssum = grp16_sum(ssum);
    const float inv = 1.0f / ssum;
    #pragma unroll
    for (int j = 0; j < 9; ++j)
        sg[l + j * 16] = ej[j] * inv;      // padding slots get 0, never read

    // ---- band stripes only (<=2 per row; fill partner wrote the rest) ----
    #pragma unroll
    for (int r = 0; r < 4; ++r) {
        const int klo = k_lo[r], khi = k_hi[r];
        const int s_lo = klo >> 8, s_hi = khi >> 8;
        float* base = Wout + (size_t)(row0 + r) * LK_;
        const float* sr = sw + r * NB_PAD;
        for (int j = s_lo; j <= s_hi; ++j) {           // <=2 iterations
            const int c0 = (j * 64 + lane) * 4;        // column of this float4
            float w[4] = {0.f, 0.f, 0.f, 0.f};
            if (c0 + 3 >= klo && c0 <= khi) {
                #pragma unroll
                for (int i = 0; i < 4; ++i) {
                    const int c = c0 + i;
                    if (c >= klo && c <= khi) w[i] = sr[c - klo];
                }
            }
            fx4 w4; w4.x = w[0]; w4.y = w[1]; w4.z = w[2]; w4.w = w[3];
            __builtin_nontemporal_store(w4, (fx4*)(base + c0));
        }
    }
}

extern "C" void kernel_launch(void* const* d_in, const int* in_sizes, int n_in,
                              void* d_out, int out_size, void* d_ws, size_t ws_size,
                              hipStream_t stream) {
    // inputs (setup_inputs order): query, key, value, mask, query_lengths, key_lengths
    const float* Q    = (const float*)d_in[0];
    const float* K    = (const float*)d_in[1];
    const float* V    = (const float*)d_in[2];
    const int*   qlen = (const int*)d_in[4];
    const int*   klen = (const int*)d_in[5];

    float* Wout = (float*)d_out;
    const size_t W_ELEMS = (size_t)B_ * LQ_ * LK_;        // 67,108,864
    float* Vout = Wout + W_ELEMS;

    stripe_attn_kernel<<<dim3(2 * NUNIT), dim3(256), 0, stream>>>(
        Q, K, V, qlen, klen, Wout, Vout);
}

// Round 16
// 96.362 us; speedup vs baseline: 1.3779x; 1.0375x over previous
//
#include <hip/hip_runtime.h>
#include <math.h>

// Problem constants (from reference)
constexpr int B_  = 16;
constexpr int LQ_ = 1024;
constexpr int LK_ = 4096;
constexpr int D_  = 256;
constexpr float HALF_BW_F = 64.0f;         // 128 // 2
constexpr float SCALE = 0.0625f;           // (D^-0.25)^2 = 1/sqrt(256)

// native clang vector for nontemporal builtins (HIP_vector_type is rejected)
typedef float fx4 __attribute__((ext_vector_type(4)));

// softmax covers 9*16 = 144 slots; pad to 168 (168 % 32 == 8 -> the 4
// per-row arrays start on different banks)
constexpr int NB_PAD = 168;
constexpr int ROWS_PER_BLK = 16;                 // 4 waves x 4 rows
constexpr int NUNIT = (B_ * LQ_) / ROWS_PER_BLK; // 1024 row-units
constexpr int NXCD = 8;
constexpr int UNIT_PER_XCD = NUNIT / NXCD;       // 128

// DPP row_shr:N — lane i receives from lane i-N (toward higher lanes) within
// the 16-lane DPP row; out-of-range sources read 0 (bound_ctrl=1). After
// shr8,shr4,shr2,shr1 the complete 16-lane sum is in the row's last lane
// (l==15).
template <int CTRL>
__device__ __forceinline__ float dpp_add(float v) {
    int x = __builtin_amdgcn_update_dpp(0, __float_as_int(v), CTRL, 0xF, 0xF, true);
    return v + __int_as_float(x);
}
__device__ __forceinline__ float dpp_reduce16(float v) {
    v = dpp_add<0x118>(v); v = dpp_add<0x114>(v);
    v = dpp_add<0x112>(v); v = dpp_add<0x111>(v);
    return v;   // complete sum in l==15
}

// reductions within a 16-lane group (xor offsets stay inside the group)
__device__ __forceinline__ float grp16_max(float v) {
    #pragma unroll
    for (int off = 8; off > 0; off >>= 1)
        v = fmaxf(v, __shfl_xor(v, off, 64));
    return v;
}
__device__ __forceinline__ float grp16_sum(float v) {
    #pragma unroll
    for (int off = 8; off > 0; off >>= 1)
        v += __shfl_xor(v, off, 64);
    return v;
}

// R12/R15 structure; lever: MEMORY-LEVEL PARALLELISM in the score loop.
// Diagnosis: VALU ~13% issue, traffic floors ~25us, yet compute ~100us and
// invariant to occupancy/layout/stores -> exposed L2 latency. Old loop
// issued 4KB of loads then waited ~300cyc (8KB in flight per CU vs ~12KB
// latency-BW product). Now each 16-lane group handles 2 keys/iter: 8 loads
// issued together, iterations halve to ~18, unroll 2 -> up to 16KB in
// flight per wave (128KB/CU). Same total VALU work.
__global__ __launch_bounds__(256, 2) void stripe_attn_kernel(
    const float* __restrict__ Q, const float* __restrict__ K,
    const float* __restrict__ V,
    const int* __restrict__ qlen, const int* __restrict__ klen,
    float* __restrict__ Wout, float* __restrict__ Vout)
{
    const int Bid  = blockIdx.x;
    const int xcd  = Bid & 7;
    const int type = (Bid >> 3) & 1;
    // unit u in [0,1024): XCD-contiguous row mapping (each XCD owns 2048
    // consecutive rows = 2 batches -> sliding K-band stays in its 4MB L2)
    const int rb   = xcd * UNIT_PER_XCD + (Bid >> 4);
    const int tid  = threadIdx.x;
    const int lane = tid & 63;
    const int wave = tid >> 6;
    const int row0 = rb * ROWS_PER_BLK + wave * 4;   // first of this wave's 4 rows
    const int b    = row0 >> 10;           // same batch for all 16 unit rows
    const int qi0  = row0 & (LQ_ - 1);

    __shared__ float s_sc[4][4 * NB_PAD];  // [wave][row*NB_PAD + slot]

    const int   key_len = klen[b];
    const float slope   = (float)key_len / (float)qlen[b];   // fp32 div (ref)

    // per-row integer band (exact fp32 arithmetic as reference)
    int k_lo[4], k_hi[4];                  // only static-indexed below
    #pragma unroll
    for (int r = 0; r < 4; ++r) {
        const float center = (float)(qi0 + r) * slope;
        int lo = (int)ceilf(center - HALF_BW_F); if (lo < 0) lo = 0;
        int hi = (int)floorf(center + HALF_BW_F); if (hi > key_len - 1) hi = key_len - 1;
        k_lo[r] = lo; k_hi[r] = hi;
    }

    if (type == 1) {
        // ================= FILL BLOCK: pure store pump =================
        const float* vs = V    + (size_t)row0 * 1024;
        float*       vd = Vout + (size_t)row0 * 1024;
        #pragma unroll
        for (int it = 0; it < 16; ++it) {
            const int o = (it * 64 + lane) * 4;
            fx4 t = __builtin_nontemporal_load((const fx4*)(vs + o));
            __builtin_nontemporal_store(t, (fx4*)(vd + o));
        }
        const fx4 z4 = {0.f, 0.f, 0.f, 0.f};
        #pragma unroll
        for (int r = 0; r < 4; ++r) {
            const int s_lo = k_lo[r] >> 8, s_hi = k_hi[r] >> 8;
            float* base = Wout + (size_t)(row0 + r) * LK_;
            #pragma unroll
            for (int j = 0; j < 16; ++j) {
                if (j < s_lo || j > s_hi)
                    __builtin_nontemporal_store(z4, (fx4*)(base + (j * 64 + lane) * 4));
            }
        }
        return;
    }

    // ================= COMPUTE BLOCK =================
    const int g   = lane >> 4;             // group 0..3
    const int l   = lane & 15;             // D-chunk 0..15 (16 floats each)
    const int lo0 = k_lo[0], hi3 = k_hi[3];    // union band (nondecreasing)

    // ---- Q staging: 4 rows x 4 float4 (lane l covers floats l*16..l*16+15)
    const float* qbase = Q + ((size_t)b * LQ_ + qi0) * D_;
    float4 q0[4], q1[4], q2[4], q3[4];
    #pragma unroll
    for (int m = 0; m < 4; ++m) {
        q0[m] = *(const float4*)(qbase + 0 * D_ + l * 16 + m * 4);
        q1[m] = *(const float4*)(qbase + 1 * D_ + l * 16 + m * 4);
        q2[m] = *(const float4*)(qbase + 2 * D_ + l * 16 + m * 4);
        q3[m] = *(const float4*)(qbase + 3 * D_ + l * 16 + m * 4);
    }

    // ---- scores: 8 keys/iter (2 per 16-lane group), each serves 4 rows ----
    const float* kbase = K + (size_t)b * LK_ * D_;
    float* sw = s_sc[wave];
    #pragma unroll 2
    for (int kk0 = lo0; kk0 <= hi3; kk0 += 8) {
        const int keyA  = kk0 + g;
        const int keyB  = kk0 + g + 4;
        const int keyAc = (keyA <= hi3) ? keyA : hi3;   // clamp: safe, in-batch
        const int keyBc = (keyB <= hi3) ? keyB : hi3;
        const float* kpA = kbase + (size_t)keyAc * D_ + l * 16;
        const float* kpB = kbase + (size_t)keyBc * D_ + l * 16;
        float4 kfA[4], kfB[4];
        #pragma unroll
        for (int m = 0; m < 4; ++m) kfA[m] = *(const float4*)(kpA + m * 4);
        #pragma unroll
        for (int m = 0; m < 4; ++m) kfB[m] = *(const float4*)(kpB + m * 4);
        float a0 = 0.f, a1 = 0.f, a2 = 0.f, a3 = 0.f;
        float b0 = 0.f, b1 = 0.f, b2 = 0.f, b3 = 0.f;
        #pragma unroll
        for (int m = 0; m < 4; ++m) {
            a0 += q0[m].x*kfA[m].x + q0[m].y*kfA[m].y + q0[m].z*kfA[m].z + q0[m].w*kfA[m].w;
            a1 += q1[m].x*kfA[m].x + q1[m].y*kfA[m].y + q1[m].z*kfA[m].z + q1[m].w*kfA[m].w;
            a2 += q2[m].x*kfA[m].x + q2[m].y*kfA[m].y + q2[m].z*kfA[m].z + q2[m].w*kfA[m].w;
            a3 += q3[m].x*kfA[m].x + q3[m].y*kfA[m].y + q3[m].z*kfA[m].z + q3[m].w*kfA[m].w;
            b0 += q0[m].x*kfB[m].x + q0[m].y*kfB[m].y + q0[m].z*kfB[m].z + q0[m].w*kfB[m].w;
            b1 += q1[m].x*kfB[m].x + q1[m].y*kfB[m].y + q1[m].z*kfB[m].z + q1[m].w*kfB[m].w;
            b2 += q2[m].x*kfB[m].x + q2[m].y*kfB[m].y + q2[m].z*kfB[m].z + q2[m].w*kfB[m].w;
            b3 += q3[m].x*kfB[m].x + q3[m].y*kfB[m].y + q3[m].z*kfB[m].z + q3[m].w*kfB[m].w;
        }
        a0 = dpp_reduce16(a0); a1 = dpp_reduce16(a1);
        a2 = dpp_reduce16(a2); a3 = dpp_reduce16(a3);
        b0 = dpp_reduce16(b0); b1 = dpp_reduce16(b1);
        b2 = dpp_reduce16(b2); b3 = dpp_reduce16(b3);
        if (l == 15) {   // unclamped key in conditions -> clamped dup never stores
            if (keyA >= k_lo[0] && keyA <= k_hi[0]) sw[0*NB_PAD + keyA - k_lo[0]] = a0 * SCALE;
            if (keyA >= k_lo[1] && keyA <= k_hi[1]) sw[1*NB_PAD + keyA - k_lo[1]] = a1 * SCALE;
            if (keyA >= k_lo[2] && keyA <= k_hi[2]) sw[2*NB_PAD + keyA - k_lo[2]] = a2 * SCALE;
            if (keyA >= k_lo[3] && keyA <= k_hi[3]) sw[3*NB_PAD + keyA - k_lo[3]] = a3 * SCALE;
            if (keyB >= k_lo[0] && keyB <= k_hi[0]) sw[0*NB_PAD + keyB - k_lo[0]] = b0 * SCALE;
            if (keyB >= k_lo[1] && keyB <= k_hi[1]) sw[1*NB_PAD + keyB - k_lo[1]] = b1 * SCALE;
            if (keyB >= k_lo[2] && keyB <= k_hi[2]) sw[2*NB_PAD + keyB - k_lo[2]] = b2 * SCALE;
            if (keyB >= k_lo[3] && keyB <= k_hi[3]) sw[3*NB_PAD + keyB - k_lo[3]] = b3 * SCALE;
        }
    }

    // ---- softmax: 16-lane group g owns row g (9 values per lane) ----
    // recompute band from scalars (k_lo[g] with runtime g would spill, rule #20)
    const float center_g = (float)(qi0 + g) * slope;
    int klo_g = (int)ceilf(center_g - HALF_BW_F); if (klo_g < 0) klo_g = 0;
    int khi_g = (int)floorf(center_g + HALF_BW_F); if (khi_g > key_len - 1) khi_g = key_len - 1;
    const int nb_g = khi_g - klo_g + 1;    // 65..129
    float* sg = sw + g * NB_PAD;

    float vj[9];
    #pragma unroll
    for (int j = 0; j < 9; ++j) {
        const int idx = l + j * 16;
        vj[j] = (idx < nb_g) ? sg[idx] : -INFINITY;
    }
    float mx = vj[0];
    #pragma unroll
    for (int j = 1; j < 9; ++j) mx = fmaxf(mx, vj[j]);
    mx = grp16_max(mx);

    float ej[9], ssum = 0.f;
    #pragma unroll
    for (int j = 0; j < 9; ++j) { ej[j] = __expf(vj[j] - mx); ssum += ej[j]; }
    ssum = grp16_sum(ssum);
    const float inv = 1.0f / ssum;
    #pragma unroll
    for (int j = 0; j < 9; ++j)
        sg[l + j * 16] = ej[j] * inv;      // padding slots get 0, never read

    // ---- band stripes only (<=2 per row; fill partner wrote the rest) ----
    #pragma unroll
    for (int r = 0; r < 4; ++r) {
        const int klo = k_lo[r], khi = k_hi[r];
        const int s_lo = klo >> 8, s_hi = khi >> 8;
        float* base = Wout + (size_t)(row0 + r) * LK_;
        const float* sr = sw + r * NB_PAD;
        for (int j = s_lo; j <= s_hi; ++j) {           // <=2 iterations
            const int c0 = (j * 64 + lane) * 4;        // column of this float4
            float w[4] = {0.f, 0.f, 0.f, 0.f};
            if (c0 + 3 >= klo && c0 <= khi) {
                #pragma unroll
                for (int i = 0; i < 4; ++i) {
                    const int c = c0 + i;
                    if (c >= klo && c <= khi) w[i] = sr[c - klo];
                }
            }
            fx4 w4; w4.x = w[0]; w4.y = w[1]; w4.z = w[2]; w4.w = w[3];
            __builtin_nontemporal_store(w4, (fx4*)(base + c0));
        }
    }
}

extern "C" void kernel_launch(void* const* d_in, const int* in_sizes, int n_in,
                              void* d_out, int out_size, void* d_ws, size_t ws_size,
                              hipStream_t stream) {
    // inputs (setup_inputs order): query, key, value, mask, query_lengths, key_lengths
    const float* Q    = (const float*)d_in[0];
    const float* K    = (const float*)d_in[1];
    const float* V    = (const float*)d_in[2];
    const int*   qlen = (const int*)d_in[4];
    const int*   klen = (const int*)d_in[5];

    float* Wout = (float*)d_out;
    const size_t W_ELEMS = (size_t)B_ * LQ_ * LK_;        // 67,108,864
    float* Vout = Wout + W_ELEMS;

    stripe_attn_kernel<<<dim3(2 * NUNIT), dim3(256), 0, stream>>>(
        Q, K, V, qlen, klen, Wout, Vout);
}